// Round 4
// baseline (937.900 us; speedup 1.0000x reference)
//
#include <hip/hip_runtime.h>
#include <hip/hip_bf16.h>

typedef __hip_bfloat16 bf16;

__device__ __forceinline__ float b2f(bf16 v) { return __bfloat162float(v); }

// dtype-flexible loads (flags resolved at runtime by sniff_kernel; branches are uniform)
__device__ __forceinline__ float loadF(const void* p, int i, int isf32) {
    return isf32 ? ((const float*)p)[i] : b2f(((const bf16*)p)[i]);
}
__device__ __forceinline__ int loadI(const void* p, long long i, int isi64) {
    return isi64 ? (int)((const long long*)p)[i] : ((const int*)p)[i];
}

// ---------------------------------------------------------------- dtype sniff
// flags[0]=1 -> float arrays are f32 (not bf16); flags[1]=1 -> edge_index is int64
__global__ void sniff_kernel(const void* xv, const void* eiv, int* flags) {
    int lane = threadIdx.x;                       // 64 threads
    const bf16* xb = (const bf16*)xv;
    int big = 0;
#pragma unroll
    for (int k = 0; k < 4; k++) {
        float v = fabsf(b2f(xb[lane * 4 + k]));   // first 256 bf16 slots of x
        if (v > 1e6f) big = 1;
    }
    unsigned long long bigmask = __ballot(big);
    const int* e32 = (const int*)eiv;
    int nz = (lane < 32) ? (e32[2 * lane + 1] != 0) : 0;  // odd slots: int64 high halves
    unsigned long long nzmask = __ballot(nz);
    if (lane == 0) {
        flags[0] = (__popcll(bigmask) >= 8) ? 1 : 0;
        flags[1] = (nzmask == 0ULL) ? 1 : 0;
    }
}

// ---------------------------------------------------------------- zero fill
__global__ void zero_kernel(float* __restrict__ p, long long cnt) {
    long long i = (long long)blockIdx.x * blockDim.x + threadIdx.x;
    if (i < cnt) p[i] = 0.f;
}

// ---------------------------------------------------------------- degree count
__global__ void count_kernel(const void* ei, float* __restrict__ deg, int E, int n,
                             const int* __restrict__ flags) {
    int e = blockIdx.x * blockDim.x + threadIdx.x;
    if (e >= E) return;
    int d = loadI(ei, (long long)E + e, flags[1]);
    if ((unsigned)d < (unsigned)n) atomicAdd(&deg[d], 1.0f);
}

// ---------------------------------------------------------------- dinv = rsqrt(deg+1)
__global__ void dinv_kernel(float* __restrict__ dinv, int n) {
    int i = blockIdx.x * blockDim.x + threadIdx.x;
    if (i < n) dinv[i] = rsqrtf(dinv[i] + 1.0f);
}

// ---------------------------------------------------------------- layer1 scatter (xw1 on the fly)
// A[d*32+j] += (x[s] @ W1)[j] * dinv[s];  32 lanes per edge
__global__ void scatter1_kernel(const void* ei, const void* xv, const void* W1v,
                                const float* __restrict__ dinv, float* __restrict__ A,
                                int E, int n, const int* __restrict__ flags) {
    __shared__ float sW1[6 * 32];
    int xf = flags[0], idf = flags[1];
    int tid = threadIdx.x;
    if (tid < 192) sW1[tid] = loadF(W1v, tid, xf);
    __syncthreads();
    long long t = (long long)blockIdx.x * blockDim.x + tid;
    int e = (int)(t >> 5), j = (int)(t & 31);
    if (e >= E) return;
    int s = loadI(ei, e, idf);
    int d = loadI(ei, (long long)E + e, idf);
    if ((unsigned)s >= (unsigned)n || (unsigned)d >= (unsigned)n) return;
    float dv = dinv[s];
    float y = 0.f;
#pragma unroll
    for (int k = 0; k < 6; k++) y = fmaf(loadF(xv, s * 6 + k, xf), sW1[k * 32 + j], y);
    atomicAdd(&A[(size_t)d * 32 + j], y * dv);
}

// ---------------------------------------------------------------- layer1 finalize + relu + (h@W2)*dinv -> Yf (f32)
__global__ void fused_mid_kernel(const float* __restrict__ A, const void* xv,
                                 const float* __restrict__ dinv,
                                 const void* W1v, const void* b1v, const void* W2v,
                                 float* __restrict__ Yf, int n, const int* __restrict__ flags) {
    __shared__ float sW1[6 * 32];
    __shared__ float sW2[32 * 32];
    __shared__ float sb1[32];
    int xf = flags[0];
    int tid = threadIdx.x;
    if (tid < 192) sW1[tid] = loadF(W1v, tid, xf);
    for (int i = tid; i < 32 * 32; i += blockDim.x) sW2[i] = loadF(W2v, i, xf);
    if (tid < 32) sb1[tid] = loadF(b1v, tid, xf);
    __syncthreads();
    long long t = (long long)blockIdx.x * blockDim.x + tid;
    int node = (int)(t >> 5), j = (int)(t & 31);
    if (node >= n) return;
    float dv = dinv[node];
    float xw = 0.f;
#pragma unroll
    for (int k = 0; k < 6; k++) xw = fmaf(loadF(xv, node * 6 + k, xf), sW1[k * 32 + j], xw);
    float h = fmaxf(dv * A[t] + dv * dv * xw + sb1[j], 0.f);
    float y2 = 0.f;
#pragma unroll
    for (int k = 0; k < 32; k++) {
        float hk = __shfl(h, k, 32);
        y2 = fmaf(hk, sW2[k * 32 + j], y2);
    }
    Yf[t] = y2 * dv;
}

// ---------------------------------------------------------------- layer2 scatter: A[d*32+j] += Yf[s*32+j]
__global__ void scatter2_kernel(const void* ei, const float* __restrict__ Yf,
                                float* __restrict__ A, int E, int n,
                                const int* __restrict__ flags) {
    int idf = flags[1];
    long long t = (long long)blockIdx.x * blockDim.x + threadIdx.x;
    int e = (int)(t >> 5), j = (int)(t & 31);
    if (e >= E) return;
    int s = loadI(ei, e, idf);
    int d = loadI(ei, (long long)E + e, idf);
    if ((unsigned)s >= (unsigned)n || (unsigned)d >= (unsigned)n) return;
    atomicAdd(&A[(size_t)d * 32 + j], Yf[(size_t)s * 32 + j]);
}

// ---------------------------------------------------------------- layer2 finalize + features + both heads
// out layout (f32): [logits n][normals 3n][uvs 3n][features 32n]; Yf aliases out+7n
__global__ void out_kernel(const float* __restrict__ A, const float* __restrict__ dinv,
                           const void* b2v,
                           const void* Wt1v, const void* bt1v, const void* Wt2v, const void* bt2v,
                           const void* Wa1v, const void* ba1v, const void* Wa2v, const void* ba2v,
                           float* __restrict__ out, int n, const int* __restrict__ flags) {
    __shared__ float sWt1[32 * 16], sWa1[32 * 16], sWt2[16], sWa2[16 * 6];
    __shared__ float sbt1[16], sba1[16], sba2[6], sb2[32];
    __shared__ float sbt2;
    int xf = flags[0];
    int tid = threadIdx.x;
    for (int i = tid; i < 32 * 16; i += blockDim.x) {
        sWt1[i] = loadF(Wt1v, i, xf);
        sWa1[i] = loadF(Wa1v, i, xf);
    }
    for (int i = tid; i < 16 * 6; i += blockDim.x) sWa2[i] = loadF(Wa2v, i, xf);
    if (tid < 16) { sWt2[tid] = loadF(Wt2v, tid, xf); sbt1[tid] = loadF(bt1v, tid, xf); sba1[tid] = loadF(ba1v, tid, xf); }
    if (tid < 32) sb2[tid] = loadF(b2v, tid, xf);
    if (tid < 6) sba2[tid] = loadF(ba2v, tid, xf);
    if (tid == 0) sbt2 = loadF(bt2v, 0, xf);
    __syncthreads();
    long long t = (long long)blockIdx.x * blockDim.x + tid;
    int node = (int)(t >> 5), j = (int)(t & 31);
    if (node >= n) return;
    float* Yf = out + (size_t)n * 7;
    float dv = dinv[node];
    float f = dv * (A[t] + Yf[t]) + sb2[j];
    Yf[t] = f;                                    // final features (own element only)
    float acc = 0.f;
#pragma unroll
    for (int k = 0; k < 32; k++) {
        float fk = __shfl(f, k, 32);
        float w = (j < 16) ? sWt1[k * 16 + j] : sWa1[k * 16 + (j - 16)];
        acc = fmaf(fk, w, acc);
    }
    float u = fmaxf(acc + ((j < 16) ? sbt1[j] : sba1[j - 16]), 0.f);
    float o = 0.f;
#pragma unroll
    for (int k = 0; k < 16; k++) {
        float ut = __shfl(u, k, 32);
        float ua = __shfl(u, 16 + k, 32);
        float w = (j == 0) ? sWt2[k] : ((j < 7) ? sWa2[k * 6 + (j - 1)] : 0.f);
        o = fmaf((j == 0) ? ut : ua, w, o);
    }
    if (j == 0)      out[node] = o + sbt2;
    else if (j < 4)  out[(size_t)n     + (size_t)node * 3 + (j - 1)] = o + sba2[j - 1];
    else if (j < 7)  out[(size_t)n * 4 + (size_t)node * 3 + (j - 4)] = o + sba2[j - 1];
}

extern "C" void kernel_launch(void* const* d_in, const int* in_sizes, int n_in,
                              void* d_out, int out_size, void* d_ws, size_t ws_size,
                              hipStream_t stream) {
    const void* x   = d_in[0];
    const void* ei  = d_in[1];
    const void* W1  = d_in[2];
    const void* b1  = d_in[3];
    const void* W2  = d_in[4];
    const void* b2  = d_in[5];
    const void* Wt1 = d_in[6];
    const void* bt1 = d_in[7];
    const void* Wt2 = d_in[8];
    const void* bt2 = d_in[9];
    const void* Wa1 = d_in[10];
    const void* ba1 = d_in[11];
    const void* Wa2 = d_in[12];
    const void* ba2 = d_in[13];

    int n = in_sizes[0] / 6;          // 150000
    int E = in_sizes[1] / 2;          // 2400000

    // workspace: [A 32n f32][dinv n_pad f32][flags]  ~= 19.9 MB
    char* ws = (char*)d_ws;
    size_t n_pad = (size_t)((n + 63) & ~63);
    float* A    = (float*)ws;
    float* dinv = (float*)(ws + (size_t)32 * n * 4);
    int* flags  = (int*)(ws + ((size_t)32 * n + n_pad) * 4);

    float* out = (float*)d_out;
    float* Yf  = out + (size_t)n * 7;  // features slot doubles as f32 Y2 scratch

    const int B = 256;
    long long zcnt = (long long)32 * n + (long long)n_pad;
    int grid_zero  = (int)((zcnt + B - 1) / B);
    int grid_zeroA = (int)(((long long)32 * n + B - 1) / B);
    int grid_nodes = (int)(((long long)n * 32 + B - 1) / B);
    int grid_edges = (int)(((long long)E * 32 + B - 1) / B);

    sniff_kernel<<<1, 64, 0, stream>>>(x, ei, flags);
    zero_kernel<<<grid_zero, B, 0, stream>>>(A, zcnt);                       // A + dinv
    count_kernel<<<(E + B - 1) / B, B, 0, stream>>>(ei, dinv, E, n, flags);
    dinv_kernel<<<(n + B - 1) / B, B, 0, stream>>>(dinv, n);
    scatter1_kernel<<<grid_edges, B, 0, stream>>>(ei, x, W1, dinv, A, E, n, flags);
    fused_mid_kernel<<<grid_nodes, B, 0, stream>>>(A, x, dinv, W1, b1, W2, Yf, n, flags);
    zero_kernel<<<grid_zeroA, B, 0, stream>>>(A, (long long)32 * n);         // re-zero A
    scatter2_kernel<<<grid_edges, B, 0, stream>>>(ei, Yf, A, E, n, flags);
    out_kernel<<<grid_nodes, B, 0, stream>>>(A, dinv, b2, Wt1, bt1, Wt2, bt2,
                                             Wa1, ba1, Wa2, ba2, out, n, flags);
}

// Round 5
// 601.128 us; speedup vs baseline: 1.5602x; 1.5602x over previous
//
#include <hip/hip_runtime.h>
#include <hip/hip_bf16.h>

typedef __hip_bfloat16 bf16;

__device__ __forceinline__ float b2f(bf16 v) { return __bfloat162float(v); }

// dtype-flexible loads (flags resolved at runtime by sniff_kernel; branches are uniform)
__device__ __forceinline__ float loadF(const void* p, int i, int isf32) {
    return isf32 ? ((const float*)p)[i] : b2f(((const bf16*)p)[i]);
}
__device__ __forceinline__ int loadI(const void* p, long long i, int isi64) {
    return isi64 ? (int)((const long long*)p)[i] : ((const int*)p)[i];
}

// ---------------------------------------------------------------- dtype sniff
__global__ void sniff_kernel(const void* xv, const void* eiv, int* flags) {
    int lane = threadIdx.x;                       // 64 threads
    const bf16* xb = (const bf16*)xv;
    int big = 0;
#pragma unroll
    for (int k = 0; k < 4; k++) {
        float v = fabsf(b2f(xb[lane * 4 + k]));
        if (v > 1e6f) big = 1;
    }
    unsigned long long bigmask = __ballot(big);
    const int* e32 = (const int*)eiv;
    int nz = (lane < 32) ? (e32[2 * lane + 1] != 0) : 0;
    unsigned long long nzmask = __ballot(nz);
    if (lane == 0) {
        flags[0] = (__popcll(bigmask) >= 8) ? 1 : 0;
        flags[1] = (nzmask == 0ULL) ? 1 : 0;
    }
}

// ---------------------------------------------------------------- fills
__global__ void zero_f32(float* __restrict__ p, long long cnt) {
    long long i = (long long)blockIdx.x * blockDim.x + threadIdx.x;
    if (i < cnt) p[i] = 0.f;
}
__global__ void zero_i32(int* __restrict__ p, long long cnt) {
    long long i = (long long)blockIdx.x * blockDim.x + threadIdx.x;
    if (i < cnt) p[i] = 0;
}

// ================================================================ CSR build
__global__ void hist_kernel(const void* ei, int* __restrict__ cnt, int E, int n,
                            const int* __restrict__ flags) {
    int e = blockIdx.x * blockDim.x + threadIdx.x;
    if (e >= E) return;
    int d = loadI(ei, (long long)E + e, flags[1]);
    if ((unsigned)d < (unsigned)n) atomicAdd(&cnt[d], 1);
}

// partial[b] = sum of cnt over chunk b (chunk = 1024)
__global__ void partial_kernel(const int* __restrict__ cnt, int* __restrict__ partial, int n) {
    __shared__ int lds[256];
    int b = blockIdx.x, t = threadIdx.x;
    int base = b * 1024 + t * 4;
    int s = 0;
#pragma unroll
    for (int k = 0; k < 4; k++) { int i = base + k; if (i < n) s += cnt[i]; }
    lds[t] = s; __syncthreads();
    for (int off = 128; off >= 1; off >>= 1) {
        if (t < off) lds[t] += lds[t + off];
        __syncthreads();
    }
    if (t == 0) partial[b] = lds[0];
}

// exclusive scan of partial[] in place (single block); rowptr[n] = total
__global__ void scanpart_kernel(int* __restrict__ partial, int* __restrict__ rowptr,
                                int npart, int n) {
    __shared__ int lds[256];
    int t = threadIdx.x;
    int v = (t < npart) ? partial[t] : 0;
    lds[t] = v; __syncthreads();
    for (int off = 1; off < 256; off <<= 1) {
        int tmp = (t >= off) ? lds[t - off] : 0;
        __syncthreads();
        lds[t] += tmp;
        __syncthreads();
    }
    if (t < npart) partial[t] = lds[t] - v;   // exclusive
    if (t == 0) rowptr[n] = lds[255];         // grand total
}

// rowptr[i] = partial[b] + exclusive-scan within chunk
__global__ void scanblk_kernel(const int* __restrict__ cnt, const int* __restrict__ partial,
                               int* __restrict__ rowptr, int n) {
    __shared__ int lds[256];
    int b = blockIdx.x, t = threadIdx.x;
    int base = b * 1024 + t * 4;
    int v[4]; int ms = 0;
#pragma unroll
    for (int k = 0; k < 4; k++) { int i = base + k; v[k] = (i < n) ? cnt[i] : 0; ms += v[k]; }
    lds[t] = ms; __syncthreads();
    for (int off = 1; off < 256; off <<= 1) {
        int tmp = (t >= off) ? lds[t - off] : 0;
        __syncthreads();
        lds[t] += tmp;
        __syncthreads();
    }
    int p = partial[b] + (lds[t] - ms);
#pragma unroll
    for (int k = 0; k < 4; k++) { int i = base + k; if (i < n) { rowptr[i] = p; p += v[k]; } }
}

// dinv = rsqrt(deg+1); zero cnt for reuse as fill cursor
__global__ void dinvcur_kernel(int* __restrict__ cnt, float* __restrict__ dinv, int n) {
    int i = blockIdx.x * blockDim.x + threadIdx.x;
    if (i < n) { dinv[i] = rsqrtf((float)cnt[i] + 1.0f); cnt[i] = 0; }
}

__global__ void fill_kernel(const void* ei, const int* __restrict__ rowptr,
                            int* __restrict__ cur, int* __restrict__ adj,
                            int E, int n, const int* __restrict__ flags) {
    int idf = flags[1];
    int e = blockIdx.x * blockDim.x + threadIdx.x;
    if (e >= E) return;
    int s = loadI(ei, e, idf);
    int d = loadI(ei, (long long)E + e, idf);
    if ((unsigned)s >= (unsigned)n || (unsigned)d >= (unsigned)n) return;
    int pos = rowptr[d] + atomicAdd(&cur[d], 1);
    adj[pos] = s;
}

// ================================================================ layer 1 gather (fused xW1 + finalize + relu + hW2)
__global__ void gcn1_kernel(const int* __restrict__ rowptr, const int* __restrict__ adj,
                            const void* xv, const void* W1v, const void* b1v, const void* W2v,
                            const float* __restrict__ dinv, float* __restrict__ Y2,
                            int n, const int* __restrict__ flags) {
    __shared__ float sW1[6 * 32];
    __shared__ float sW2[32 * 32];
    __shared__ float sb1[32];
    int xf = flags[0];
    int tid = threadIdx.x;
    if (tid < 192) sW1[tid] = loadF(W1v, tid, xf);
    for (int i = tid; i < 1024; i += blockDim.x) sW2[i] = loadF(W2v, i, xf);
    if (tid < 32) sb1[tid] = loadF(b1v, tid, xf);
    __syncthreads();
    long long t = (long long)blockIdx.x * blockDim.x + tid;
    int node = (int)(t >> 5), j = (int)(t & 31);
    if (node >= n) return;
    int base = rowptr[node], end = rowptr[node + 1];
    float agg = 0.f;
    for (int i0 = base; i0 < end; i0 += 32) {
        int m = end - i0;                 // remaining edges (>=1)
        int sv = 0; float dvv = 0.f;
        float x0 = 0, x1 = 0, x2 = 0, x3 = 0, x4 = 0, x5 = 0;
        if (j < m) {
            sv = adj[i0 + j];
            dvv = dinv[sv];
            int o = sv * 6;
            x0 = loadF(xv, o,     xf); x1 = loadF(xv, o + 1, xf); x2 = loadF(xv, o + 2, xf);
            x3 = loadF(xv, o + 3, xf); x4 = loadF(xv, o + 4, xf); x5 = loadF(xv, o + 5, xf);
        }
        int mm = (m < 32) ? m : 32;
        for (int kk = 0; kk < mm; kk++) {
            float xa = __shfl(x0, kk, 32), xb = __shfl(x1, kk, 32), xc = __shfl(x2, kk, 32);
            float xd = __shfl(x3, kk, 32), xe = __shfl(x4, kk, 32), xg = __shfl(x5, kk, 32);
            float dvs = __shfl(dvv, kk, 32);
            float y = xa * sW1[0 * 32 + j];
            y = fmaf(xb, sW1[1 * 32 + j], y);
            y = fmaf(xc, sW1[2 * 32 + j], y);
            y = fmaf(xd, sW1[3 * 32 + j], y);
            y = fmaf(xe, sW1[4 * 32 + j], y);
            y = fmaf(xg, sW1[5 * 32 + j], y);
            agg = fmaf(y, dvs, agg);
        }
    }
    float dv = dinv[node];
    float xw = 0.f;
    {
        int o = node * 6;
#pragma unroll
        for (int k = 0; k < 6; k++) xw = fmaf(loadF(xv, o + k, xf), sW1[k * 32 + j], xw);
    }
    float h = fmaxf(fmaf(dv, agg, fmaf(dv * dv, xw, sb1[j])), 0.f);
    float y2 = 0.f;
#pragma unroll
    for (int kk = 0; kk < 32; kk++) {
        y2 = fmaf(__shfl(h, kk, 32), sW2[kk * 32 + j], y2);
    }
    Y2[(size_t)node * 32 + j] = y2 * dv;
}

// ================================================================ layer 2 gather (fused finalize + features + both heads)
// out layout (f32): [logits n][normals 3n][uvs 3n][features 32n]
__global__ void gcn2_kernel(const int* __restrict__ rowptr, const int* __restrict__ adj,
                            const float* __restrict__ Y2, const float* __restrict__ dinv,
                            const void* b2v,
                            const void* Wt1v, const void* bt1v, const void* Wt2v, const void* bt2v,
                            const void* Wa1v, const void* ba1v, const void* Wa2v, const void* ba2v,
                            float* __restrict__ out, int n, const int* __restrict__ flags) {
    __shared__ float sWt1[32 * 16], sWa1[32 * 16], sWt2[16], sWa2[16 * 6];
    __shared__ float sbt1[16], sba1[16], sba2[6], sb2[32];
    __shared__ float sbt2;
    int xf = flags[0];
    int tid = threadIdx.x;
    for (int i = tid; i < 32 * 16; i += blockDim.x) {
        sWt1[i] = loadF(Wt1v, i, xf);
        sWa1[i] = loadF(Wa1v, i, xf);
    }
    for (int i = tid; i < 16 * 6; i += blockDim.x) sWa2[i] = loadF(Wa2v, i, xf);
    if (tid < 16) { sWt2[tid] = loadF(Wt2v, tid, xf); sbt1[tid] = loadF(bt1v, tid, xf); sba1[tid] = loadF(ba1v, tid, xf); }
    if (tid < 32) sb2[tid] = loadF(b2v, tid, xf);
    if (tid < 6) sba2[tid] = loadF(ba2v, tid, xf);
    if (tid == 0) sbt2 = loadF(bt2v, 0, xf);
    __syncthreads();
    long long t = (long long)blockIdx.x * blockDim.x + tid;
    int node = (int)(t >> 5), j = (int)(t & 31);
    if (node >= n) return;
    int base = rowptr[node], end = rowptr[node + 1];
    float agg = 0.f;
    for (int i0 = base; i0 < end; i0 += 32) {
        int m = end - i0;
        int sv = (j < m) ? adj[i0 + j] : 0;
        int mm = (m < 32) ? m : 32;
        int kk = 0;
        for (; kk + 4 <= mm; kk += 4) {
            int s0 = __shfl(sv, kk, 32), s1 = __shfl(sv, kk + 1, 32);
            int s2 = __shfl(sv, kk + 2, 32), s3 = __shfl(sv, kk + 3, 32);
            float a0 = Y2[(size_t)s0 * 32 + j];
            float a1 = Y2[(size_t)s1 * 32 + j];
            float a2 = Y2[(size_t)s2 * 32 + j];
            float a3 = Y2[(size_t)s3 * 32 + j];
            agg += (a0 + a1) + (a2 + a3);
        }
        for (; kk < mm; kk++) {
            int s0 = __shfl(sv, kk, 32);
            agg += Y2[(size_t)s0 * 32 + j];
        }
    }
    float dv = dinv[node];
    float f = fmaf(dv, agg + Y2[(size_t)node * 32 + j], sb2[j]);
    out[(size_t)n * 7 + (size_t)node * 32 + j] = f;   // features
    float acc = 0.f;
#pragma unroll
    for (int k = 0; k < 32; k++) {
        float fk = __shfl(f, k, 32);
        float w = (j < 16) ? sWt1[k * 16 + j] : sWa1[k * 16 + (j - 16)];
        acc = fmaf(fk, w, acc);
    }
    float u = fmaxf(acc + ((j < 16) ? sbt1[j] : sba1[j - 16]), 0.f);
    float o = 0.f;
#pragma unroll
    for (int k = 0; k < 16; k++) {
        float ut = __shfl(u, k, 32);
        float ua = __shfl(u, 16 + k, 32);
        float w = (j == 0) ? sWt2[k] : ((j < 7) ? sWa2[k * 6 + (j - 1)] : 0.f);
        o = fmaf((j == 0) ? ut : ua, w, o);
    }
    if (j == 0)      out[node] = o + sbt2;
    else if (j < 4)  out[(size_t)n     + (size_t)node * 3 + (j - 1)] = o + sba2[j - 1];
    else if (j < 7)  out[(size_t)n * 4 + (size_t)node * 3 + (j - 4)] = o + sba2[j - 1];
}

// ================================================================ fallback (round-4 scatter path) kernels
__global__ void count_kernel(const void* ei, float* __restrict__ deg, int E, int n,
                             const int* __restrict__ flags) {
    int e = blockIdx.x * blockDim.x + threadIdx.x;
    if (e >= E) return;
    int d = loadI(ei, (long long)E + e, flags[1]);
    if ((unsigned)d < (unsigned)n) atomicAdd(&deg[d], 1.0f);
}
__global__ void dinv_kernel(float* __restrict__ dinv, int n) {
    int i = blockIdx.x * blockDim.x + threadIdx.x;
    if (i < n) dinv[i] = rsqrtf(dinv[i] + 1.0f);
}
__global__ void scatter1_kernel(const void* ei, const void* xv, const void* W1v,
                                const float* __restrict__ dinv, float* __restrict__ A,
                                int E, int n, const int* __restrict__ flags) {
    __shared__ float sW1[6 * 32];
    int xf = flags[0], idf = flags[1];
    int tid = threadIdx.x;
    if (tid < 192) sW1[tid] = loadF(W1v, tid, xf);
    __syncthreads();
    long long t = (long long)blockIdx.x * blockDim.x + tid;
    int e = (int)(t >> 5), j = (int)(t & 31);
    if (e >= E) return;
    int s = loadI(ei, e, idf);
    int d = loadI(ei, (long long)E + e, idf);
    if ((unsigned)s >= (unsigned)n || (unsigned)d >= (unsigned)n) return;
    float dv = dinv[s];
    float y = 0.f;
#pragma unroll
    for (int k = 0; k < 6; k++) y = fmaf(loadF(xv, s * 6 + k, xf), sW1[k * 32 + j], y);
    atomicAdd(&A[(size_t)d * 32 + j], y * dv);
}
__global__ void fused_mid_kernel(const float* __restrict__ A, const void* xv,
                                 const float* __restrict__ dinv,
                                 const void* W1v, const void* b1v, const void* W2v,
                                 float* __restrict__ Yf, int n, const int* __restrict__ flags) {
    __shared__ float sW1[6 * 32];
    __shared__ float sW2[32 * 32];
    __shared__ float sb1[32];
    int xf = flags[0];
    int tid = threadIdx.x;
    if (tid < 192) sW1[tid] = loadF(W1v, tid, xf);
    for (int i = tid; i < 32 * 32; i += blockDim.x) sW2[i] = loadF(W2v, i, xf);
    if (tid < 32) sb1[tid] = loadF(b1v, tid, xf);
    __syncthreads();
    long long t = (long long)blockIdx.x * blockDim.x + tid;
    int node = (int)(t >> 5), j = (int)(t & 31);
    if (node >= n) return;
    float dv = dinv[node];
    float xw = 0.f;
#pragma unroll
    for (int k = 0; k < 6; k++) xw = fmaf(loadF(xv, node * 6 + k, xf), sW1[k * 32 + j], xw);
    float h = fmaxf(dv * A[t] + dv * dv * xw + sb1[j], 0.f);
    float y2 = 0.f;
#pragma unroll
    for (int k = 0; k < 32; k++) y2 = fmaf(__shfl(h, k, 32), sW2[k * 32 + j], y2);
    Yf[t] = y2 * dv;
}
__global__ void scatter2_kernel(const void* ei, const float* __restrict__ Yf,
                                float* __restrict__ A, int E, int n,
                                const int* __restrict__ flags) {
    int idf = flags[1];
    long long t = (long long)blockIdx.x * blockDim.x + threadIdx.x;
    int e = (int)(t >> 5), j = (int)(t & 31);
    if (e >= E) return;
    int s = loadI(ei, e, idf);
    int d = loadI(ei, (long long)E + e, idf);
    if ((unsigned)s >= (unsigned)n || (unsigned)d >= (unsigned)n) return;
    atomicAdd(&A[(size_t)d * 32 + j], Yf[(size_t)s * 32 + j]);
}
__global__ void out_kernel(const float* __restrict__ A, const float* __restrict__ dinv,
                           const void* b2v,
                           const void* Wt1v, const void* bt1v, const void* Wt2v, const void* bt2v,
                           const void* Wa1v, const void* ba1v, const void* Wa2v, const void* ba2v,
                           float* __restrict__ out, int n, const int* __restrict__ flags) {
    __shared__ float sWt1[32 * 16], sWa1[32 * 16], sWt2[16], sWa2[16 * 6];
    __shared__ float sbt1[16], sba1[16], sba2[6], sb2[32];
    __shared__ float sbt2;
    int xf = flags[0];
    int tid = threadIdx.x;
    for (int i = tid; i < 32 * 16; i += blockDim.x) { sWt1[i] = loadF(Wt1v, i, xf); sWa1[i] = loadF(Wa1v, i, xf); }
    for (int i = tid; i < 16 * 6; i += blockDim.x) sWa2[i] = loadF(Wa2v, i, xf);
    if (tid < 16) { sWt2[tid] = loadF(Wt2v, tid, xf); sbt1[tid] = loadF(bt1v, tid, xf); sba1[tid] = loadF(ba1v, tid, xf); }
    if (tid < 32) sb2[tid] = loadF(b2v, tid, xf);
    if (tid < 6) sba2[tid] = loadF(ba2v, tid, xf);
    if (tid == 0) sbt2 = loadF(bt2v, 0, xf);
    __syncthreads();
    long long t = (long long)blockIdx.x * blockDim.x + tid;
    int node = (int)(t >> 5), j = (int)(t & 31);
    if (node >= n) return;
    float* Yf = out + (size_t)n * 7;
    float dv = dinv[node];
    float f = dv * (A[t] + Yf[t]) + sb2[j];
    Yf[t] = f;
    float acc = 0.f;
#pragma unroll
    for (int k = 0; k < 32; k++) {
        float fk = __shfl(f, k, 32);
        float w = (j < 16) ? sWt1[k * 16 + j] : sWa1[k * 16 + (j - 16)];
        acc = fmaf(fk, w, acc);
    }
    float u = fmaxf(acc + ((j < 16) ? sbt1[j] : sba1[j - 16]), 0.f);
    float o = 0.f;
#pragma unroll
    for (int k = 0; k < 16; k++) {
        float ut = __shfl(u, k, 32);
        float ua = __shfl(u, 16 + k, 32);
        float w = (j == 0) ? sWt2[k] : ((j < 7) ? sWa2[k * 6 + (j - 1)] : 0.f);
        o = fmaf((j == 0) ? ut : ua, w, o);
    }
    if (j == 0)      out[node] = o + sbt2;
    else if (j < 4)  out[(size_t)n     + (size_t)node * 3 + (j - 1)] = o + sba2[j - 1];
    else if (j < 7)  out[(size_t)n * 4 + (size_t)node * 3 + (j - 4)] = o + sba2[j - 1];
}

extern "C" void kernel_launch(void* const* d_in, const int* in_sizes, int n_in,
                              void* d_out, int out_size, void* d_ws, size_t ws_size,
                              hipStream_t stream) {
    const void* x   = d_in[0];
    const void* ei  = d_in[1];
    const void* W1  = d_in[2];
    const void* b1  = d_in[3];
    const void* W2  = d_in[4];
    const void* b2  = d_in[5];
    const void* Wt1 = d_in[6];
    const void* bt1 = d_in[7];
    const void* Wt2 = d_in[8];
    const void* bt2 = d_in[9];
    const void* Wa1 = d_in[10];
    const void* ba1 = d_in[11];
    const void* Wa2 = d_in[12];
    const void* ba2 = d_in[13];

    int n = in_sizes[0] / 6;          // 150000
    int E = in_sizes[1] / 2;          // 2400000

    const int B = 256;
    float* out = (float*)d_out;
    char* ws = (char*)d_ws;

    // ---------------- gather-path workspace layout (4B words) ----------------
    size_t nw    = (size_t)((n + 1 + 63) & ~63);   // rowptr slot (n+1, padded)
    size_t w_row = 0;
    size_t w_cnt = w_row + nw;
    size_t w_div = w_cnt + nw;
    size_t w_par = w_div + nw;
    size_t w_flg = w_par + 256;
    size_t w_adj = w_flg + 64;
    size_t w_y2  = w_adj + (size_t)E;
    size_t need  = (w_y2 + (size_t)32 * n) * 4;

    if (ws_size >= need) {
        int*   rowptr  = (int*)(ws + w_row * 4);
        int*   cnt     = (int*)(ws + w_cnt * 4);
        float* dinv    = (float*)(ws + w_div * 4);
        int*   partial = (int*)(ws + w_par * 4);
        int*   flags   = (int*)(ws + w_flg * 4);
        int*   adj     = (int*)(ws + w_adj * 4);
        float* Y2      = (float*)(ws + w_y2 * 4);

        int npart = (n + 1023) / 1024;
        int grid_nodes32 = (int)(((long long)n * 32 + B - 1) / B);

        sniff_kernel<<<1, 64, 0, stream>>>(x, ei, flags);
        zero_i32<<<(int)((nw + B - 1) / B), B, 0, stream>>>(cnt, (long long)nw);
        hist_kernel<<<(E + B - 1) / B, B, 0, stream>>>(ei, cnt, E, n, flags);
        partial_kernel<<<npart, B, 0, stream>>>(cnt, partial, n);
        scanpart_kernel<<<1, B, 0, stream>>>(partial, rowptr, npart, n);
        scanblk_kernel<<<npart, B, 0, stream>>>(cnt, partial, rowptr, n);
        dinvcur_kernel<<<(n + B - 1) / B, B, 0, stream>>>(cnt, dinv, n);
        fill_kernel<<<(E + B - 1) / B, B, 0, stream>>>(ei, rowptr, cnt, adj, E, n, flags);
        gcn1_kernel<<<grid_nodes32, B, 0, stream>>>(rowptr, adj, x, W1, b1, W2, dinv, Y2, n, flags);
        gcn2_kernel<<<grid_nodes32, B, 0, stream>>>(rowptr, adj, Y2, dinv, b2,
                                                    Wt1, bt1, Wt2, bt2, Wa1, ba1, Wa2, ba2,
                                                    out, n, flags);
        return;
    }

    // ---------------- fallback: round-4 scatter path ----------------
    size_t n_pad = (size_t)((n + 63) & ~63);
    float* A    = (float*)ws;
    float* dinv = (float*)(ws + (size_t)32 * n * 4);
    int* flags  = (int*)(ws + ((size_t)32 * n + n_pad) * 4);
    float* Yf   = out + (size_t)n * 7;

    long long zcnt = (long long)32 * n + (long long)n_pad;
    int grid_zero  = (int)((zcnt + B - 1) / B);
    int grid_zeroA = (int)(((long long)32 * n + B - 1) / B);
    int grid_nodes = (int)(((long long)n * 32 + B - 1) / B);
    int grid_edges = (int)(((long long)E * 32 + B - 1) / B);

    sniff_kernel<<<1, 64, 0, stream>>>(x, ei, flags);
    zero_f32<<<grid_zero, B, 0, stream>>>(A, zcnt);
    count_kernel<<<(E + B - 1) / B, B, 0, stream>>>(ei, dinv, E, n, flags);
    dinv_kernel<<<(n + B - 1) / B, B, 0, stream>>>(dinv, n);
    scatter1_kernel<<<grid_edges, B, 0, stream>>>(ei, x, W1, dinv, A, E, n, flags);
    fused_mid_kernel<<<grid_nodes, B, 0, stream>>>(A, x, dinv, W1, b1, W2, Yf, n, flags);
    zero_f32<<<grid_zeroA, B, 0, stream>>>(A, (long long)32 * n);
    scatter2_kernel<<<grid_edges, B, 0, stream>>>(ei, Yf, A, E, n, flags);
    out_kernel<<<grid_nodes, B, 0, stream>>>(A, dinv, b2, Wt1, bt1, Wt2, bt2,
                                             Wa1, ba1, Wa2, ba2, out, n, flags);
}

// Round 6
// 532.850 us; speedup vs baseline: 1.7602x; 1.1281x over previous
//
#include <hip/hip_runtime.h>
#include <hip/hip_bf16.h>

typedef __hip_bfloat16 bf16;

__device__ __forceinline__ float b2f(bf16 v) { return __bfloat162float(v); }
__device__ __forceinline__ bf16  f2b(float v){ return __float2bfloat16(v); }

// dtype-flexible loads (flags resolved at runtime by sniff_kernel; branches are uniform)
__device__ __forceinline__ float loadF(const void* p, int i, int isf32) {
    return isf32 ? ((const float*)p)[i] : b2f(((const bf16*)p)[i]);
}
__device__ __forceinline__ int loadI(const void* p, long long i, int isi64) {
    return isi64 ? (int)((const long long*)p)[i] : ((const int*)p)[i];
}

// ---------------------------------------------------------------- dtype sniff
__global__ void sniff_kernel(const void* xv, const void* eiv, int* flags) {
    int lane = threadIdx.x;                       // 64 threads
    const bf16* xb = (const bf16*)xv;
    int big = 0;
#pragma unroll
    for (int k = 0; k < 4; k++) {
        float v = fabsf(b2f(xb[lane * 4 + k]));
        if (v > 1e6f) big = 1;
    }
    unsigned long long bigmask = __ballot(big);
    const int* e32 = (const int*)eiv;
    int nz = (lane < 32) ? (e32[2 * lane + 1] != 0) : 0;
    unsigned long long nzmask = __ballot(nz);
    if (lane == 0) {
        flags[0] = (__popcll(bigmask) >= 8) ? 1 : 0;
        flags[1] = (nzmask == 0ULL) ? 1 : 0;
    }
}

// ---------------------------------------------------------------- fills
__global__ void zero_f32(float* __restrict__ p, long long cnt) {
    long long i = (long long)blockIdx.x * blockDim.x + threadIdx.x;
    if (i < cnt) p[i] = 0.f;
}
__global__ void zero_i32(int* __restrict__ p, long long cnt) {
    long long i = (long long)blockIdx.x * blockDim.x + threadIdx.x;
    if (i < cnt) p[i] = 0;
}

// ================================================================ CSR build
__global__ void hist_kernel(const void* ei, int* __restrict__ cnt, int E, int n,
                            const int* __restrict__ flags) {
    int e = blockIdx.x * blockDim.x + threadIdx.x;
    if (e >= E) return;
    int d = loadI(ei, (long long)E + e, flags[1]);
    if ((unsigned)d < (unsigned)n) atomicAdd(&cnt[d], 1);
}

// partial[b] = sum of cnt over chunk b (chunk = 1024)
__global__ void partial_kernel(const int* __restrict__ cnt, int* __restrict__ partial, int n) {
    __shared__ int lds[256];
    int b = blockIdx.x, t = threadIdx.x;
    int base = b * 1024 + t * 4;
    int s = 0;
#pragma unroll
    for (int k = 0; k < 4; k++) { int i = base + k; if (i < n) s += cnt[i]; }
    lds[t] = s; __syncthreads();
    for (int off = 128; off >= 1; off >>= 1) {
        if (t < off) lds[t] += lds[t + off];
        __syncthreads();
    }
    if (t == 0) partial[b] = lds[0];
}

// exclusive scan of partial[] in place (single block); rowptr[n] = total
__global__ void scanpart_kernel(int* __restrict__ partial, int* __restrict__ rowptr,
                                int npart, int n) {
    __shared__ int lds[256];
    int t = threadIdx.x;
    int v = (t < npart) ? partial[t] : 0;
    lds[t] = v; __syncthreads();
    for (int off = 1; off < 256; off <<= 1) {
        int tmp = (t >= off) ? lds[t - off] : 0;
        __syncthreads();
        lds[t] += tmp;
        __syncthreads();
    }
    if (t < npart) partial[t] = lds[t] - v;   // exclusive
    if (t == 0) rowptr[n] = lds[255];         // grand total
}

// rowptr[i] = partial[b] + exclusive-scan within chunk
__global__ void scanblk_kernel(const int* __restrict__ cnt, const int* __restrict__ partial,
                               int* __restrict__ rowptr, int n) {
    __shared__ int lds[256];
    int b = blockIdx.x, t = threadIdx.x;
    int base = b * 1024 + t * 4;
    int v[4]; int ms = 0;
#pragma unroll
    for (int k = 0; k < 4; k++) { int i = base + k; v[k] = (i < n) ? cnt[i] : 0; ms += v[k]; }
    lds[t] = ms; __syncthreads();
    for (int off = 1; off < 256; off <<= 1) {
        int tmp = (t >= off) ? lds[t - off] : 0;
        __syncthreads();
        lds[t] += tmp;
        __syncthreads();
    }
    int p = partial[b] + (lds[t] - ms);
#pragma unroll
    for (int k = 0; k < 4; k++) { int i = base + k; if (i < n) { rowptr[i] = p; p += v[k]; } }
}

// dinv = rsqrt(deg+1); z[i] = [x*dinv (6), dinv, 0]; zero cnt for reuse as fill cursor
__global__ void prep_kernel(int* __restrict__ cnt, float* __restrict__ dinv,
                            float* __restrict__ z, const void* xv, int n,
                            const int* __restrict__ flags) {
    int i = blockIdx.x * blockDim.x + threadIdx.x;
    if (i >= n) return;
    int xf = flags[0];
    float dv = rsqrtf((float)cnt[i] + 1.0f);
    dinv[i] = dv; cnt[i] = 0;
    float* zr = z + (size_t)i * 8;
#pragma unroll
    for (int k = 0; k < 6; k++) zr[k] = loadF(xv, i * 6 + k, xf) * dv;
    zr[6] = dv; zr[7] = 0.f;
}

__global__ void fill_kernel(const void* ei, const int* __restrict__ rowptr,
                            int* __restrict__ cur, int* __restrict__ adj,
                            int E, int n, const int* __restrict__ flags) {
    int idf = flags[1];
    int e = blockIdx.x * blockDim.x + threadIdx.x;
    if (e >= E) return;
    int s = loadI(ei, e, idf);
    int d = loadI(ei, (long long)E + e, idf);
    if ((unsigned)s >= (unsigned)n || (unsigned)d >= (unsigned)n) return;
    int pos = rowptr[d] + atomicAdd(&cur[d], 1);
    __builtin_nontemporal_store(s, &adj[pos]);
}

// ================================================================ layer 1: aggregate 6-dim z, then W1 once per node
// S6 = z[node] + sum_{s in N(node)} z[s];  h = relu(dinv*(S6@W1)+b1);  Y2b = bf16((h@W2)*dinv)
__global__ void gcn1_kernel(const int* __restrict__ rowptr, const int* __restrict__ adj,
                            const float* __restrict__ z,
                            const void* W1v, const void* b1v, const void* W2v,
                            bf16* __restrict__ Y2b, int n, const int* __restrict__ flags) {
    __shared__ float sW1[6 * 32];
    __shared__ float sW2[32 * 32];
    __shared__ float sb1[32];
    int xf = flags[0];
    int tid = threadIdx.x;
    if (tid < 192) sW1[tid] = loadF(W1v, tid, xf);
    for (int i = tid; i < 1024; i += blockDim.x) sW2[i] = loadF(W2v, i, xf);
    if (tid < 32) sb1[tid] = loadF(b1v, tid, xf);
    __syncthreads();
    long long t = (long long)blockIdx.x * blockDim.x + tid;
    int node = (int)(t >> 5), j = (int)(t & 31);
    if (node >= n) return;
    int base = rowptr[node], end = rowptr[node + 1];
    // 16 edges per iteration: lane pair (j>>1) owns one edge, (j&1) picks float4 half of 32B z row
    float a0 = 0.f, a1 = 0.f, a2 = 0.f, a3 = 0.f;
    int half4 = (j & 1) * 4;
    for (int i0 = base; i0 < end; i0 += 16) {
        int eidx = i0 + (j >> 1);
        if (eidx < end) {
            int s = adj[eidx];
            const float4 v = *(const float4*)(z + (size_t)s * 8 + half4);
            a0 += v.x; a1 += v.y; a2 += v.z; a3 += v.w;
        }
    }
#pragma unroll
    for (int off = 2; off <= 16; off <<= 1) {
        a0 += __shfl_xor(a0, off, 32); a1 += __shfl_xor(a1, off, 32);
        a2 += __shfl_xor(a2, off, 32); a3 += __shfl_xor(a3, off, 32);
    }
    float S0 = __shfl(a0, 0, 32), S1 = __shfl(a1, 0, 32), S2 = __shfl(a2, 0, 32);
    float S3 = __shfl(a3, 0, 32), S4 = __shfl(a0, 1, 32), S5 = __shfl(a1, 1, 32);
    const float* zs = z + (size_t)node * 8;   // uniform within group (broadcast)
    float dv = zs[6];
    S0 += zs[0]; S1 += zs[1]; S2 += zs[2]; S3 += zs[3]; S4 += zs[4]; S5 += zs[5];
    float v = S0 * sW1[j];
    v = fmaf(S1, sW1[32 + j], v);
    v = fmaf(S2, sW1[64 + j], v);
    v = fmaf(S3, sW1[96 + j], v);
    v = fmaf(S4, sW1[128 + j], v);
    v = fmaf(S5, sW1[160 + j], v);
    float h = fmaxf(fmaf(dv, v, sb1[j]), 0.f);
    float y2 = 0.f;
#pragma unroll
    for (int kk = 0; kk < 32; kk++) y2 = fmaf(__shfl(h, kk, 32), sW2[kk * 32 + j], y2);
    Y2b[(size_t)node * 32 + j] = f2b(y2 * dv);
}

// ================================================================ layer 2: bf16 gathers + finalize + features + heads
// out layout (f32): [logits n][normals 3n][uvs 3n][features 32n]
__global__ void gcn2_kernel(const int* __restrict__ rowptr, const int* __restrict__ adj,
                            const bf16* __restrict__ Y2b, const float* __restrict__ dinv,
                            const void* b2v,
                            const void* Wt1v, const void* bt1v, const void* Wt2v, const void* bt2v,
                            const void* Wa1v, const void* ba1v, const void* Wa2v, const void* ba2v,
                            float* __restrict__ out, int n, const int* __restrict__ flags) {
    __shared__ float sWt1[32 * 16], sWa1[32 * 16], sWt2[16], sWa2[16 * 6];
    __shared__ float sbt1[16], sba1[16], sba2[6], sb2[32];
    __shared__ float sbt2;
    int xf = flags[0];
    int tid = threadIdx.x;
    for (int i = tid; i < 32 * 16; i += blockDim.x) {
        sWt1[i] = loadF(Wt1v, i, xf);
        sWa1[i] = loadF(Wa1v, i, xf);
    }
    for (int i = tid; i < 16 * 6; i += blockDim.x) sWa2[i] = loadF(Wa2v, i, xf);
    if (tid < 16) { sWt2[tid] = loadF(Wt2v, tid, xf); sbt1[tid] = loadF(bt1v, tid, xf); sba1[tid] = loadF(ba1v, tid, xf); }
    if (tid < 32) sb2[tid] = loadF(b2v, tid, xf);
    if (tid < 6) sba2[tid] = loadF(ba2v, tid, xf);
    if (tid == 0) sbt2 = loadF(bt2v, 0, xf);
    __syncthreads();
    long long t = (long long)blockIdx.x * blockDim.x + tid;
    int node = (int)(t >> 5), j = (int)(t & 31);
    if (node >= n) return;
    int base = rowptr[node], end = rowptr[node + 1];
    float agg = 0.f;
    for (int i0 = base; i0 < end; i0 += 32) {
        int rem = end - i0;
        int sv = (j < rem) ? adj[i0 + j] : 0;
        int mm = (rem < 32) ? rem : 32;
        int kk = 0;
        for (; kk + 4 <= mm; kk += 4) {
            int s0 = __shfl(sv, kk, 32), s1 = __shfl(sv, kk + 1, 32);
            int s2 = __shfl(sv, kk + 2, 32), s3 = __shfl(sv, kk + 3, 32);
            float q0 = b2f(Y2b[(size_t)s0 * 32 + j]);
            float q1 = b2f(Y2b[(size_t)s1 * 32 + j]);
            float q2 = b2f(Y2b[(size_t)s2 * 32 + j]);
            float q3 = b2f(Y2b[(size_t)s3 * 32 + j]);
            agg += (q0 + q1) + (q2 + q3);
        }
        for (; kk < mm; kk++) {
            int s0 = __shfl(sv, kk, 32);
            agg += b2f(Y2b[(size_t)s0 * 32 + j]);
        }
    }
    float dv = dinv[node];
    float f = fmaf(dv, agg + b2f(Y2b[(size_t)node * 32 + j]), sb2[j]);
    __builtin_nontemporal_store(f, &out[(size_t)n * 7 + (size_t)node * 32 + j]);  // features
    float acc = 0.f;
#pragma unroll
    for (int k = 0; k < 32; k++) {
        float fk = __shfl(f, k, 32);
        float w = (j < 16) ? sWt1[k * 16 + j] : sWa1[k * 16 + (j - 16)];
        acc = fmaf(fk, w, acc);
    }
    float u = fmaxf(acc + ((j < 16) ? sbt1[j] : sba1[j - 16]), 0.f);
    float o = 0.f;
#pragma unroll
    for (int k = 0; k < 16; k++) {
        float ut = __shfl(u, k, 32);
        float ua = __shfl(u, 16 + k, 32);
        float w = (j == 0) ? sWt2[k] : ((j < 7) ? sWa2[k * 6 + (j - 1)] : 0.f);
        o = fmaf((j == 0) ? ut : ua, w, o);
    }
    if (j == 0)      out[node] = o + sbt2;
    else if (j < 4)  out[(size_t)n     + (size_t)node * 3 + (j - 1)] = o + sba2[j - 1];
    else if (j < 7)  out[(size_t)n * 4 + (size_t)node * 3 + (j - 4)] = o + sba2[j - 1];
}

// ================================================================ fallback (round-4 scatter path) kernels
__global__ void count_kernel(const void* ei, float* __restrict__ deg, int E, int n,
                             const int* __restrict__ flags) {
    int e = blockIdx.x * blockDim.x + threadIdx.x;
    if (e >= E) return;
    int d = loadI(ei, (long long)E + e, flags[1]);
    if ((unsigned)d < (unsigned)n) atomicAdd(&deg[d], 1.0f);
}
__global__ void dinv_kernel(float* __restrict__ dinv, int n) {
    int i = blockIdx.x * blockDim.x + threadIdx.x;
    if (i < n) dinv[i] = rsqrtf(dinv[i] + 1.0f);
}
__global__ void scatter1_kernel(const void* ei, const void* xv, const void* W1v,
                                const float* __restrict__ dinv, float* __restrict__ A,
                                int E, int n, const int* __restrict__ flags) {
    __shared__ float sW1[6 * 32];
    int xf = flags[0], idf = flags[1];
    int tid = threadIdx.x;
    if (tid < 192) sW1[tid] = loadF(W1v, tid, xf);
    __syncthreads();
    long long t = (long long)blockIdx.x * blockDim.x + tid;
    int e = (int)(t >> 5), j = (int)(t & 31);
    if (e >= E) return;
    int s = loadI(ei, e, idf);
    int d = loadI(ei, (long long)E + e, idf);
    if ((unsigned)s >= (unsigned)n || (unsigned)d >= (unsigned)n) return;
    float dv = dinv[s];
    float y = 0.f;
#pragma unroll
    for (int k = 0; k < 6; k++) y = fmaf(loadF(xv, s * 6 + k, xf), sW1[k * 32 + j], y);
    atomicAdd(&A[(size_t)d * 32 + j], y * dv);
}
__global__ void fused_mid_kernel(const float* __restrict__ A, const void* xv,
                                 const float* __restrict__ dinv,
                                 const void* W1v, const void* b1v, const void* W2v,
                                 float* __restrict__ Yf, int n, const int* __restrict__ flags) {
    __shared__ float sW1[6 * 32];
    __shared__ float sW2[32 * 32];
    __shared__ float sb1[32];
    int xf = flags[0];
    int tid = threadIdx.x;
    if (tid < 192) sW1[tid] = loadF(W1v, tid, xf);
    for (int i = tid; i < 32 * 32; i += blockDim.x) sW2[i] = loadF(W2v, i, xf);
    if (tid < 32) sb1[tid] = loadF(b1v, tid, xf);
    __syncthreads();
    long long t = (long long)blockIdx.x * blockDim.x + tid;
    int node = (int)(t >> 5), j = (int)(t & 31);
    if (node >= n) return;
    float dv = dinv[node];
    float xw = 0.f;
#pragma unroll
    for (int k = 0; k < 6; k++) xw = fmaf(loadF(xv, node * 6 + k, xf), sW1[k * 32 + j], xw);
    float h = fmaxf(dv * A[t] + dv * dv * xw + sb1[j], 0.f);
    float y2 = 0.f;
#pragma unroll
    for (int k = 0; k < 32; k++) y2 = fmaf(__shfl(h, k, 32), sW2[k * 32 + j], y2);
    Yf[t] = y2 * dv;
}
__global__ void scatter2_kernel(const void* ei, const float* __restrict__ Yf,
                                float* __restrict__ A, int E, int n,
                                const int* __restrict__ flags) {
    int idf = flags[1];
    long long t = (long long)blockIdx.x * blockDim.x + threadIdx.x;
    int e = (int)(t >> 5), j = (int)(t & 31);
    if (e >= E) return;
    int s = loadI(ei, e, idf);
    int d = loadI(ei, (long long)E + e, idf);
    if ((unsigned)s >= (unsigned)n || (unsigned)d >= (unsigned)n) return;
    atomicAdd(&A[(size_t)d * 32 + j], Yf[(size_t)s * 32 + j]);
}
__global__ void out_kernel(const float* __restrict__ A, const float* __restrict__ dinv,
                           const void* b2v,
                           const void* Wt1v, const void* bt1v, const void* Wt2v, const void* bt2v,
                           const void* Wa1v, const void* ba1v, const void* Wa2v, const void* ba2v,
                           float* __restrict__ out, int n, const int* __restrict__ flags) {
    __shared__ float sWt1[32 * 16], sWa1[32 * 16], sWt2[16], sWa2[16 * 6];
    __shared__ float sbt1[16], sba1[16], sba2[6], sb2[32];
    __shared__ float sbt2;
    int xf = flags[0];
    int tid = threadIdx.x;
    for (int i = tid; i < 32 * 16; i += blockDim.x) { sWt1[i] = loadF(Wt1v, i, xf); sWa1[i] = loadF(Wa1v, i, xf); }
    for (int i = tid; i < 16 * 6; i += blockDim.x) sWa2[i] = loadF(Wa2v, i, xf);
    if (tid < 16) { sWt2[tid] = loadF(Wt2v, tid, xf); sbt1[tid] = loadF(bt1v, tid, xf); sba1[tid] = loadF(ba1v, tid, xf); }
    if (tid < 32) sb2[tid] = loadF(b2v, tid, xf);
    if (tid < 6) sba2[tid] = loadF(ba2v, tid, xf);
    if (tid == 0) sbt2 = loadF(bt2v, 0, xf);
    __syncthreads();
    long long t = (long long)blockIdx.x * blockDim.x + tid;
    int node = (int)(t >> 5), j = (int)(t & 31);
    if (node >= n) return;
    float* Yf = out + (size_t)n * 7;
    float dv = dinv[node];
    float f = dv * (A[t] + Yf[t]) + sb2[j];
    Yf[t] = f;
    float acc = 0.f;
#pragma unroll
    for (int k = 0; k < 32; k++) {
        float fk = __shfl(f, k, 32);
        float w = (j < 16) ? sWt1[k * 16 + j] : sWa1[k * 16 + (j - 16)];
        acc = fmaf(fk, w, acc);
    }
    float u = fmaxf(acc + ((j < 16) ? sbt1[j] : sba1[j - 16]), 0.f);
    float o = 0.f;
#pragma unroll
    for (int k = 0; k < 16; k++) {
        float ut = __shfl(u, k, 32);
        float ua = __shfl(u, 16 + k, 32);
        float w = (j == 0) ? sWt2[k] : ((j < 7) ? sWa2[k * 6 + (j - 1)] : 0.f);
        o = fmaf((j == 0) ? ut : ua, w, o);
    }
    if (j == 0)      out[node] = o + sbt2;
    else if (j < 4)  out[(size_t)n     + (size_t)node * 3 + (j - 1)] = o + sba2[j - 1];
    else if (j < 7)  out[(size_t)n * 4 + (size_t)node * 3 + (j - 4)] = o + sba2[j - 1];
}

extern "C" void kernel_launch(void* const* d_in, const int* in_sizes, int n_in,
                              void* d_out, int out_size, void* d_ws, size_t ws_size,
                              hipStream_t stream) {
    const void* x   = d_in[0];
    const void* ei  = d_in[1];
    const void* W1  = d_in[2];
    const void* b1  = d_in[3];
    const void* W2  = d_in[4];
    const void* b2  = d_in[5];
    const void* Wt1 = d_in[6];
    const void* bt1 = d_in[7];
    const void* Wt2 = d_in[8];
    const void* bt2 = d_in[9];
    const void* Wa1 = d_in[10];
    const void* ba1 = d_in[11];
    const void* Wa2 = d_in[12];
    const void* ba2 = d_in[13];

    int n = in_sizes[0] / 6;          // 150000
    int E = in_sizes[1] / 2;          // 2400000

    const int B = 256;
    float* out = (float*)d_out;
    char* ws = (char*)d_ws;

    // ---------------- gather-path workspace layout (4B words, 32B-aligned blocks) ----
    size_t nw    = (size_t)((n + 1 + 63) & ~63);   // rowptr slot (n+1, padded)
    size_t Ew    = (size_t)((E + 7) & ~7);
    size_t w_row = 0;
    size_t w_cnt = w_row + nw;
    size_t w_div = w_cnt + nw;
    size_t w_par = w_div + nw;
    size_t w_flg = w_par + 256;
    size_t w_z   = w_flg + 64;                     // z: n x 8 f32 (32B rows)
    size_t w_adj = w_z + (size_t)8 * n;
    size_t w_y2b = w_adj + Ew;                     // Y2b: n x 32 bf16 = 16n words
    size_t need  = (w_y2b + (size_t)16 * n) * 4;

    if (ws_size >= need) {
        int*   rowptr  = (int*)(ws + w_row * 4);
        int*   cnt     = (int*)(ws + w_cnt * 4);
        float* dinv    = (float*)(ws + w_div * 4);
        int*   partial = (int*)(ws + w_par * 4);
        int*   flags   = (int*)(ws + w_flg * 4);
        float* z       = (float*)(ws + w_z * 4);
        int*   adj     = (int*)(ws + w_adj * 4);
        bf16*  Y2b     = (bf16*)(ws + w_y2b * 4);

        int npart = (n + 1023) / 1024;
        int grid_nodes32 = (int)(((long long)n * 32 + B - 1) / B);

        sniff_kernel<<<1, 64, 0, stream>>>(x, ei, flags);
        zero_i32<<<(int)((nw + B - 1) / B), B, 0, stream>>>(cnt, (long long)nw);
        hist_kernel<<<(E + B - 1) / B, B, 0, stream>>>(ei, cnt, E, n, flags);
        partial_kernel<<<npart, B, 0, stream>>>(cnt, partial, n);
        scanpart_kernel<<<1, B, 0, stream>>>(partial, rowptr, npart, n);
        scanblk_kernel<<<npart, B, 0, stream>>>(cnt, partial, rowptr, n);
        prep_kernel<<<(n + B - 1) / B, B, 0, stream>>>(cnt, dinv, z, x, n, flags);
        fill_kernel<<<(E + B - 1) / B, B, 0, stream>>>(ei, rowptr, cnt, adj, E, n, flags);
        gcn1_kernel<<<grid_nodes32, B, 0, stream>>>(rowptr, adj, z, W1, b1, W2, Y2b, n, flags);
        gcn2_kernel<<<grid_nodes32, B, 0, stream>>>(rowptr, adj, Y2b, dinv, b2,
                                                    Wt1, bt1, Wt2, bt2, Wa1, ba1, Wa2, ba2,
                                                    out, n, flags);
        return;
    }

    // ---------------- fallback: round-4 scatter path ----------------
    size_t n_pad = (size_t)((n + 63) & ~63);
    float* A    = (float*)ws;
    float* dinv = (float*)(ws + (size_t)32 * n * 4);
    int* flags  = (int*)(ws + ((size_t)32 * n + n_pad) * 4);
    float* Yf   = out + (size_t)n * 7;

    long long zcnt = (long long)32 * n + (long long)n_pad;
    int grid_zero  = (int)((zcnt + B - 1) / B);
    int grid_zeroA = (int)(((long long)32 * n + B - 1) / B);
    int grid_nodes = (int)(((long long)n * 32 + B - 1) / B);
    int grid_edges = (int)(((long long)E * 32 + B - 1) / B);

    sniff_kernel<<<1, 64, 0, stream>>>(x, ei, flags);
    zero_f32<<<grid_zero, B, 0, stream>>>(A, zcnt);
    count_kernel<<<(E + B - 1) / B, B, 0, stream>>>(ei, dinv, E, n, flags);
    dinv_kernel<<<(n + B - 1) / B, B, 0, stream>>>(dinv, n);
    scatter1_kernel<<<grid_edges, B, 0, stream>>>(ei, x, W1, dinv, A, E, n, flags);
    fused_mid_kernel<<<grid_nodes, B, 0, stream>>>(A, x, dinv, W1, b1, W2, Yf, n, flags);
    zero_f32<<<grid_zeroA, B, 0, stream>>>(A, (long long)32 * n);
    scatter2_kernel<<<grid_edges, B, 0, stream>>>(ei, Yf, A, E, n, flags);
    out_kernel<<<grid_nodes, B, 0, stream>>>(A, dinv, b2, Wt1, bt1, Wt2, bt2,
                                             Wa1, ba1, Wa2, ba2, out, n, flags);
}